// Round 7
// baseline (735.242 us; speedup 1.0000x reference)
//
#include <hip/hip_runtime.h>
#include <hip/hip_bf16.h>
#include <hip/hip_fp16.h>
#include <math.h>

// Problem constants
#define B 32
#define N 128
#define BT (B*N)          // 4096
#define WD 100
#define UD 25
#define D 125             // LSTM hidden per direction
#define G4 (4*D)          // 500 gates
#define H2 (2*D)          // 250
#define HID 100
#define L 50

// Fast, overflow-safe activations on v_exp_f32
__device__ __forceinline__ float fast_tanh(float x) {
    float e = __expf(2.0f * x);
    return 1.0f - 2.0f / (e + 1.0f);
}
__device__ __forceinline__ float fast_sigmoid(float x) {
    return 1.0f / (1.0f + __expf(-x));
}
__device__ __forceinline__ float bcast_lane(float v, int k) {
    return __builtin_bit_cast(float, __builtin_amdgcn_readlane(__builtin_bit_cast(int, v), k));
}
__device__ __forceinline__ unsigned bcast_lane_u(unsigned v, int k) {
    return (unsigned)__builtin_amdgcn_readlane((int)v, k);
}

// pack two f32 into one u32 of 2 f16 (lo, hi), RTNE
__device__ __forceinline__ unsigned pack_f16x2(float lo, float hi) {
    __half hl = __float2half_rn(lo), hh = __float2half_rn(hi);
    unsigned a = (unsigned)__builtin_bit_cast(unsigned short, hl);
    unsigned b = (unsigned)__builtin_bit_cast(unsigned short, hh);
    return a | (b << 16);
}

typedef _Float16 h2_t __attribute__((ext_vector_type(2)));
// acc += w.lo*h.lo + w.hi*h.hi   (fp32 accumulate)
__device__ __forceinline__ float dot2acc(unsigned wu, unsigned hu, float acc) {
#if __has_builtin(__builtin_amdgcn_fdot2)
    return __builtin_amdgcn_fdot2(__builtin_bit_cast(h2_t, wu),
                                  __builtin_bit_cast(h2_t, hu), acc, false);
#else
    h2_t wv = __builtin_bit_cast(h2_t, wu);
    h2_t hv = __builtin_bit_cast(h2_t, hu);
    acc = fmaf((float)wv[0], (float)hv[0], acc);
    acc = fmaf((float)wv[1], (float)hv[1], acc);
    return acc;
#endif
}

// ---------------------------------------------------------------------------
// K_setup: ONE launch for {12 weight transposes, embedding gather, fused
// biases, WhT pad zeroing}. Grid partition: [0,TR) transpose tiles,
// [TR,TR+2048) embed (2 bt/block), then 9 bias blocks, then 48 pad blocks.
// ---------------------------------------------------------------------------
struct TJob { const float* src; float* dst; int R, C, ldo, coff, tile0, tiles_x; };
struct TArgs { TJob j[12]; };

__global__ __launch_bounds__(256)
void setup_fused(TArgs a, int n_tr,
                 const int* __restrict__ wids, const int* __restrict__ uids,
                 const float* __restrict__ wl, const float* __restrict__ tl,
                 float* __restrict__ words,
                 const float* __restrict__ l0f_b, const float* __restrict__ l0b_b,
                 const float* __restrict__ l1f_b, const float* __restrict__ l1b_b,
                 const float* __restrict__ eh_b, const float* __restrict__ em_b,
                 const float* __restrict__ lm_b,
                 float* __restrict__ b_l0, float* __restrict__ b_l1,
                 float* __restrict__ b_s3,
                 float* __restrict__ p0, float* __restrict__ p1,
                 float* __restrict__ p2, float* __restrict__ p3) {
    __shared__ float tile[32][33];
    int bid = blockIdx.x;
    int tid = threadIdx.x;
    if (bid < n_tr) {                    // ---- transpose tiles ----
        int ji = 0;
        #pragma unroll
        for (int i = 1; i < 12; i++) if (bid >= a.j[i].tile0) ji = i;
        TJob jb = a.j[ji];
        int t = bid - jb.tile0;
        int tx = t % jb.tiles_x, ty = t / jb.tiles_x;
        int txx = tid & 31, tyy = tid >> 5;      // 32 x 8
        int k0 = tx*32, n0 = ty*32;
        #pragma unroll
        for (int dy = 0; dy < 32; dy += 8) {
            int n = n0 + tyy + dy, k = k0 + txx;
            if (n < jb.R && k < jb.C)
                tile[tyy+dy][txx] = jb.src[(size_t)n*jb.C + k];
        }
        __syncthreads();
        #pragma unroll
        for (int dy = 0; dy < 32; dy += 8) {
            int k = k0 + tyy + dy, n = n0 + txx;
            if (k < jb.C && n < jb.R)
                jb.dst[(size_t)k*jb.ldo + jb.coff + n] = tile[txx][tyy+dy];
        }
        return;
    }
    bid -= n_tr;
    if (bid < 2048) {                    // ---- embed: 2 bt per block ----
        int bt = bid*2 + (tid >> 7);
        int t = tid & 127;
        int wid = wids[bt], uid = uids[bt];
        if (t < WD)       words[bt*D + t] = wl[(size_t)wid*WD + t];
        else if (t < D)   words[bt*D + t] = tl[(size_t)uid*UD + (t - WD)];
        return;
    }
    bid -= 2048;
    if (bid < 9) {                       // ---- fused biases ----
        int t = bid*256 + tid;
        if (t < 500)        b_l0[t] = l0f_b[t];
        else if (t < 1000)  b_l0[t] = l0b_b[t-500];
        else if (t < 1500)  b_l1[t-1000] = l1f_b[t-1000];
        else if (t < 2000)  b_l1[t-1000] = l1b_b[t-1500];
        else if (t < 2100)  b_s3[t-2000] = eh_b[t-2000];
        else if (t < 2200)  b_s3[t-2000] = em_b[t-2100];
        else if (t < 2300)  b_s3[t-2000] = lm_b[t-2200];
        return;
    }
    bid -= 9;                            // ---- WhT pad zeroing (48 blocks) ----
    // WhT layout [128][512]: transpose fills k<125, col<500. Zero the rest:
    //   region A: k<125, col 500..511  (125*12 = 1500)
    //   region B: k 125..127, col 0..511 (3*512 = 1536)   total 3036 per buf
    int e = bid*256 + tid;               // < 12288; need 4*3036 = 12144
    if (e < 12144) {
        int m = e / 3036, o = e % 3036;
        float* p = (m == 0) ? p0 : (m == 1) ? p1 : (m == 2) ? p2 : p3;
        if (o < 1500) {
            int k = o / 12, cc = 500 + (o % 12);
            p[k*512 + cc] = 0.0f;
        } else {
            int o2 = o - 1500;
            p[(125 + (o2 >> 9))*512 + (o2 & 511)] = 0.0f;
        }
    }
}

// ---------------------------------------------------------------------------
// K2: projection GEMM, transposed weights, CPT columns per thread,
//     software-pipelined WT loads (prefetch next k-group).
// ---------------------------------------------------------------------------
#define MT 16
template<int CPT, int BD>
__device__ __forceinline__
void proj_body(const float* __restrict__ x, const float* __restrict__ WT,
               const float* __restrict__ bias, float* __restrict__ out,
               int Ncols, int K, int ldx, const int* __restrict__ gather_idx,
               int blk, float* xs) {
    int m0 = blk * MT;
    for (int e = threadIdx.x; e < MT * K; e += BD) {
        int r = e / K, k = e - r * K;
        int m = m0 + r;
        int row = m;
        if (gather_idx) {
            int bb = m >> 7, np = m & 127;
            row = (bb << 7) + (np == 0 ? 0 : gather_idx[m]);
        }
        xs[k*17 + r] = x[(size_t)row*ldx + k];
    }
    __syncthreads();
    int n0 = threadIdx.x;
    int lane = threadIdx.x & 63;
    float acc[CPT][MT];
    int ncl[CPT];
    #pragma unroll
    for (int j = 0; j < CPT; j++) {
        int n = n0 + j*BD;
        ncl[j] = (n < Ncols) ? n : (Ncols - 1);
        #pragma unroll
        for (int r = 0; r < MT; r++) acc[j][r] = 0.0f;
    }
    float wkc[4][CPT];
    #pragma unroll
    for (int q = 0; q < 4; q++)
        #pragma unroll
        for (int j = 0; j < CPT; j++)
            wkc[q][j] = WT[(size_t)q*Ncols + ncl[j]];
    int k0 = 0;
    for (; k0 + 8 <= K; k0 += 4) {
        float xv = xs[(k0 + (lane >> 4))*17 + (lane & 15)];
        float wkn[4][CPT];
        #pragma unroll
        for (int q = 0; q < 4; q++)
            #pragma unroll
            for (int j = 0; j < CPT; j++)
                wkn[q][j] = WT[(size_t)(k0 + 4 + q)*Ncols + ncl[j]];
        #pragma unroll
        for (int q = 0; q < 4; q++) {
            #pragma unroll
            for (int r = 0; r < 16; r++) {
                float hv = bcast_lane(xv, q*16 + r);
                #pragma unroll
                for (int j = 0; j < CPT; j++)
                    acc[j][r] = fmaf(wkc[q][j], hv, acc[j][r]);
            }
        }
        #pragma unroll
        for (int q = 0; q < 4; q++)
            #pragma unroll
            for (int j = 0; j < CPT; j++)
                wkc[q][j] = wkn[q][j];
    }
    { // last full group
        float xv = xs[(k0 + (lane >> 4))*17 + (lane & 15)];
        #pragma unroll
        for (int q = 0; q < 4; q++) {
            #pragma unroll
            for (int r = 0; r < 16; r++) {
                float hv = bcast_lane(xv, q*16 + r);
                #pragma unroll
                for (int j = 0; j < CPT; j++)
                    acc[j][r] = fmaf(wkc[q][j], hv, acc[j][r]);
            }
        }
        k0 += 4;
    }
    for (; k0 < K; k0++) {
        float xv = xs[k0*17 + (lane & 15)];
        float wk[CPT];
        #pragma unroll
        for (int j = 0; j < CPT; j++) wk[j] = WT[(size_t)k0*Ncols + ncl[j]];
        #pragma unroll
        for (int r = 0; r < 16; r++) {
            float hv = bcast_lane(xv, r);
            #pragma unroll
            for (int j = 0; j < CPT; j++)
                acc[j][r] = fmaf(wk[j], hv, acc[j][r]);
        }
    }
    #pragma unroll
    for (int j = 0; j < CPT; j++) {
        int n = n0 + j*BD;
        if (n < Ncols) {
            float bb = bias[n];
            #pragma unroll
            for (int r = 0; r < MT; r++) out[(size_t)(m0 + r)*Ncols + n] = acc[j][r] + bb;
        }
    }
}

__global__ __launch_bounds__(512)
void proj_t(const float* __restrict__ x, const float* __restrict__ WT,
            const float* __restrict__ bias, float* __restrict__ out,
            int Ncols, int K, int ldx) {
    __shared__ float xs[250 * 17 + 16];
    proj_body<2, 512>(x, WT, bias, out, Ncols, K, ldx, nullptr, blockIdx.x, xs);
}

// fused scorer projections: blocks [0,256) -> s3 (Ncols=300), [256,512) -> lh
__global__ __launch_bounds__(256)
void proj_s3lh(const float* __restrict__ x,
               const float* __restrict__ WTa, const float* __restrict__ ba,
               float* __restrict__ outa,
               const float* __restrict__ WTb, const float* __restrict__ bb,
               float* __restrict__ outb, const int* __restrict__ gather_idx) {
    __shared__ float xs[250 * 17 + 16];
    int job = blockIdx.x >> 8;
    int blk = blockIdx.x & 255;
    if (job == 0)
        proj_body<2, 256>(x, WTa, ba, outa, 300, H2, H2, nullptr, blk, xs);
    else
        proj_body<2, 256>(x, WTb, bb, outb, 100, H2, H2, gather_idx, blk, xs);
}

// ---------------------------------------------------------------------------
// K3: LSTM scan v7 — LDS-RESIDENT fp16 weights + v_dot2_f32_f16.
// Post-mortem of v1-v6: the RA never allocates >~100 VGPRs here (52/80/80/
// 52/100 measured), so register-resident weights always spilled and
// re-streamed 256-360 KB/block/step from L2/scratch (~1900-2700 cyc/step =
// the whole 117-198 us). LDS storage is allocator-proof: W fp32 = 250 KB
// doesn't fit, fp16 = 125 KB does (h recurrence stays fp32; only W·h goes
// through f16: rel err 2^-11, gate RMS err ~1e-4).
// 1024 threads = 16 waves. Wave w: k-slice ks=w>>1 (16 k's), cols c0..c0+3
// (cg=(w&1)*64+lane). Weights packed as f16 k-pairs in [pk][tid][4 u32]
// layout (16B/lane stride -> conflict-free ds_read_b128; each thread stages
// exactly what it consumes). Per step: 8 ds_read + 8 readlane (f16x2 h-pair)
// + 32 fdot2. Gate phase: lanes<16 of every wave (redundant per pair so
// readlane stays intra-wave). Two lgkm-only barriers/step (no vmcnt drain).
// LDS floor: 128 KB/step / 256 B/cyc = 512 cyc/step -> ~45-55 us expected.
// ---------------------------------------------------------------------------
__global__ __launch_bounds__(1024, 4)
void lstm_scan(const float* __restrict__ xgc,
               const float* __restrict__ WhTf, const float* __restrict__ WhTb,
               float* __restrict__ out) {
    extern __shared__ float smem[];
    unsigned* wlds = (unsigned*)smem;        // [8 pk][1024 tid][4 u32] = 128 KB
    float* pbuf = smem + 32768;              // [8][512] = 16 KB
    int dir = blockIdx.x & 1;
    int b = blockIdx.x >> 1;
    const float* WhT = dir ? WhTb : WhTf;    // [128][512] fp32, zero-padded
    int off = dir ? D : 0;
    int t = threadIdx.x;
    int lane = t & 63;
    int w = t >> 6;                  // wave 0..15
    int ks = w >> 1;                 // k-slice 0..7 (rows ks*16..ks*16+15)
    int cg = ((w & 1) << 6) + lane;  // col-group 0..127
    int c0 = cg << 2;                // first col 0..508

    // ---- stage weights: fp32 global -> f16-pair LDS (one-time) ----
    #pragma unroll
    for (int pk = 0; pk < 8; pk++) {
        int kr = ks*16 + pk*2;
        float4 wa = *(const float4*)&WhT[(size_t)kr*512 + c0];
        float4 wb = *(const float4*)&WhT[(size_t)(kr+1)*512 + c0];
        uint4 u;
        u.x = pack_f16x2(wa.x, wb.x);
        u.y = pack_f16x2(wa.y, wb.y);
        u.z = pack_f16x2(wa.z, wb.z);
        u.w = pack_f16x2(wa.w, wb.w);
        *(uint4*)&wlds[((pk << 10) + t) << 2] = u;
    }
    __syncthreads();

    const float* xb = xgc + (size_t)b * N * 1000 + dir * 500;
    bool xa = (ks == 0) && (cg < 125);
    float4 zero4 = make_float4(0.f, 0.f, 0.f, 0.f);
    float4 xA = zero4, xB = zero4;           // depth-2 x prefetch
    if (xa) {
        xA = *(const float4*)&xb[(size_t)(dir ? (N-1) : 0)*1000 + c0];
        xB = *(const float4*)&xb[(size_t)(dir ? (N-2) : 1)*1000 + c0];
    }

    int t4 = ks*16 + lane;                   // gate row (valid for lane<16)
    bool gl = (lane < 16);
    bool sto = gl && (t4 < 125) && ((w & 1) == 0);

    unsigned vhp = 0;                        // f16x2 pair (h[2j],h[2j+1]) at even lane 2j
    float c = 0.0f, h = 0.0f;

    for (int ti = 0; ti < N; ti++) {
        int tt = dir ? (N-1-ti) : ti;
        float4 x_cur = xA;
        float4 xC = zero4;
        if (xa && ti + 2 < N) {
            int tn = dir ? (tt-2) : (tt+2);
            xC = *(const float4*)&xb[(size_t)tn*1000 + c0];
        }
        float a0 = x_cur.x, a1 = x_cur.y, a2 = x_cur.z, a3 = x_cur.w;
        #pragma unroll
        for (int pk = 0; pk < 8; pk++) {
            uint4 wq = *(const uint4*)&wlds[((pk << 10) + t) << 2];
            unsigned hp = bcast_lane_u(vhp, 2*pk);   // pair lives at even lane 2*pk
            a0 = dot2acc(wq.x, hp, a0);
            a1 = dot2acc(wq.y, hp, a1);
            a2 = dot2acc(wq.z, hp, a2);
            a3 = dot2acc(wq.w, hp, a3);
        }
        xA = xB; xB = xC;
        *(float4*)&pbuf[ks*512 + c0] = make_float4(a0, a1, a2, a3);
        // lgkm-only barrier (global x loads stay in flight)
        asm volatile("s_waitcnt lgkmcnt(0)" ::: "memory");
        __builtin_amdgcn_s_barrier();
        asm volatile("" ::: "memory");
        if (gl) {        // every wave computes its slice's gates (t4>=125 -> benign junk, W rows zeroed)
            float iv = 0.f, fv = 0.f, gv = 0.f, ov = 0.f;
            #pragma unroll
            for (int s = 0; s < 8; s++) {
                const float* ps = &pbuf[s*512];
                iv += ps[t4];
                fv += ps[125 + t4];
                gv += ps[250 + t4];
                ov += ps[375 + t4];
            }
            float si = fast_sigmoid(iv);
            float sf = fast_sigmoid(fv);
            float so = fast_sigmoid(ov);
            c = sf * c + si * fast_tanh(gv);
            h = so * fast_tanh(c);
            if (sto)
                out[(size_t)(b*N + tt)*H2 + off + t4] = h;
        }
        float hn = __shfl_xor(h, 1);
        vhp = pack_f16x2(h, hn);             // even lanes: (h[2j], h[2j+1])
        // barrier 2: gate-phase pbuf reads must retire before next write
        asm volatile("s_waitcnt lgkmcnt(0)" ::: "memory");
        __builtin_amdgcn_s_barrier();
        asm volatile("" ::: "memory");
    }
}

// ---------------------------------------------------------------------------
// K4: fused arc + rel. Blocks [0,1024): arc (b, 4-i tile); [1024,5120): rel.
// ---------------------------------------------------------------------------
#define ITILE 4
__global__ __launch_bounds__(128)
void arc_rel(const float* __restrict__ s3,
             const float* __restrict__ esW, const float* __restrict__ esb,
             const int* __restrict__ ta, const float* __restrict__ rh,
             const float* __restrict__ lsW, const float* __restrict__ lsb,
             float* __restrict__ arc_out, float* __restrict__ tree_out,
             float* __restrict__ rel_out, float* __restrict__ pred_out) {
    __shared__ float wms[128 * 101];
    __shared__ float whs[ITILE][HID];
    __shared__ float es[HID];
    __shared__ float sv[128];
    __shared__ int   si[128];
    int j = threadIdx.x;

    if (blockIdx.x < 1024) {             // ---------- arc ----------
        int blk = blockIdx.x;
        int b = blk >> 5, it = blk & 31;
        for (int e = j; e < 128 * HID; e += 128) {
            int r = e / HID, h = e - r * HID;
            wms[r*101 + h] = s3[(size_t)(b*N + r)*300 + 100 + h];
        }
        for (int e = j; e < ITILE * HID; e += 128) {
            int ii = e / HID, h = e - ii * HID;
            whs[ii][h] = s3[(size_t)(b*N + it*ITILE + ii)*300 + h];
        }
        if (j < HID) es[j] = esW[j];
        __syncthreads();
        float eb = esb[0];
        const float* wmr = &wms[j * 101];
        for (int ii = 0; ii < ITILE; ii++) {
            int i = it * ITILE + ii;
            int bi = b * N + i;
            float acc = 0.0f;
            for (int h = 0; h < HID; h++)
                acc = fmaf(es[h], fast_tanh(whs[ii][h] + wmr[h]), acc);
            int tai = (i == 0) ? 0 : ta[bi];
            float score = acc + eb + 1.0f - ((j == tai) ? 1.0f : 0.0f);
            arc_out[(size_t)bi*N + j] = score;
            sv[j] = score; si[j] = j;
            __syncthreads();
            for (int s = 64; s; s >>= 1) {
                if (j < s) {
                    float ov = sv[j+s]; int oi = si[j+s];
                    if (ov > sv[j] || (ov == sv[j] && oi < si[j])) { sv[j] = ov; si[j] = oi; }
                }
                __syncthreads();
            }
            if (j == 0) tree_out[bi] = (float)si[0];
            __syncthreads();
        }
    } else {                             // ---------- rel ----------
        int bt = blockIdx.x - 1024;
        float* tv = es;                  // reuse 100-float buffer
        if (j < HID)
            tv[j] = fast_tanh(s3[(size_t)bt*300 + 200 + j] + rh[(size_t)bt*HID + j]);
        __syncthreads();
        float score = -1e30f;
        if (j < L) {
            float acc = 0.0f;
            const float* wrow = lsW + j*HID;
            for (int h = 0; h < HID; h++) acc = fmaf(wrow[h], tv[h], acc);
            score = acc + lsb[j];
            rel_out[(size_t)bt*L + j] = score;
        }
        sv[j] = score; si[j] = j;
        __syncthreads();
        for (int s = 64; s; s >>= 1) {
            if (j < s) {
                float ov = sv[j+s]; int oi = si[j+s];
                if (ov > sv[j] || (ov == sv[j] && oi < si[j])) { sv[j] = ov; si[j] = oi; }
            }
            __syncthreads();
        }
        if (j == 0) pred_out[bt] = (float)si[0];
    }
}

// ---------------------------------------------------------------------------
extern "C" void kernel_launch(void* const* d_in, const int* in_sizes, int n_in,
                              void* d_out, int out_size, void* d_ws, size_t ws_size,
                              hipStream_t stream) {
    const int*   word_ids    = (const int*)  d_in[0];
    const int*   upos_ids    = (const int*)  d_in[1];
    const int*   target_arcs = (const int*)  d_in[2];
    const float* wlookup     = (const float*)d_in[3];
    const float* tlookup     = (const float*)d_in[4];
    const float* l0f_Wih = (const float*)d_in[5];
    const float* l0f_Whh = (const float*)d_in[6];
    const float* l0f_b   = (const float*)d_in[7];
    const float* l0b_Wih = (const float*)d_in[8];
    const float* l0b_Whh = (const float*)d_in[9];
    const float* l0b_b   = (const float*)d_in[10];
    const float* l1f_Wih = (const float*)d_in[11];
    const float* l1f_Whh = (const float*)d_in[12];
    const float* l1f_b   = (const float*)d_in[13];
    const float* l1b_Wih = (const float*)d_in[14];
    const float* l1b_Whh = (const float*)d_in[15];
    const float* l1b_b   = (const float*)d_in[16];
    const float* eh_W = (const float*)d_in[17];
    const float* eh_b = (const float*)d_in[18];
    const float* em_W = (const float*)d_in[19];
    const float* em_b = (const float*)d_in[20];
    const float* es_W = (const float*)d_in[21];
    const float* es_b = (const float*)d_in[22];
    const float* lh_W = (const float*)d_in[23];
    const float* lh_b = (const float*)d_in[24];
    const float* lm_W = (const float*)d_in[25];
    const float* lm_b = (const float*)d_in[26];
    const float* ls_W = (const float*)d_in[27];
    const float* ls_b = (const float*)d_in[28];

    float* out = (float*)d_out;
    float* trees_out = out;                         // 4096
    float* preds_out = out + BT;                    // 4096
    float* arc_out   = out + 2*BT;                  // 524288
    float* rel_out   = out + 2*BT + BT*N;           // 204800

    float* ws = (float*)d_ws;
    float* A       = ws;                    // 4,096,000: xg fused [m][1000]; later s3 [m][300]
    float* words   = ws + 4096000;          //   512,000
    float* C       = ws + 4608000;          // 1,024,000: h0, then ex
    float* WT_l0   = ws + 5632000;          //   125,000  [125][1000]
    float* WT_l1   = ws + 5757000;          //   250,000  [250][1000]
    float* WT_s3   = ws + 6007000;          //    75,000  [250][300]
    float* WT_lh   = ws + 6082000;          //    25,000  [250][100]
    float* WhT_l0f = ws + 6107000;          //    65,536  [128][512] (pads zeroed)
    float* WhT_l0b = ws + 6172536;          //    65,536
    float* WhT_l1f = ws + 6238072;          //    65,536
    float* WhT_l1b = ws + 6303608;          //    65,536
    float* b_l0    = ws + 6369144;          //     1,000
    float* b_l1    = ws + 6370144;          //     1,000
    float* b_s3    = ws + 6371144;          //     1,000 (300 used)
    float* rel_head = ws + 6372144;         //   409,600  [m][100]
    // total 6,781,744 floats = 27.1 MB

    // one-time: allow >64KB dynamic LDS for lstm_scan (no-op on some ROCm)
    static bool attr_done = false;
    if (!attr_done) {
        (void)hipFuncSetAttribute(reinterpret_cast<const void*>(lstm_scan),
                                  hipFuncAttributeMaxDynamicSharedMemorySize,
                                  147456);
        attr_done = true;
    }

    // 0. single fused setup launch
    TArgs ta{};
    int n_tr = 0;
    {
        auto tiles = [](int R, int C_) { return ((C_+31)/32) * ((R+31)/32); };
        struct { const float* s; float* d; int R, C, ldo, coff; } js[12] = {
            { l0f_Wih, WT_l0, 500, 125, 1000, 0 },
            { l0b_Wih, WT_l0, 500, 125, 1000, 500 },
            { l1f_Wih, WT_l1, 500, 250, 1000, 0 },
            { l1b_Wih, WT_l1, 500, 250, 1000, 500 },
            { eh_W, WT_s3, 100, 250, 300, 0 },
            { em_W, WT_s3, 100, 250, 300, 100 },
            { lm_W, WT_s3, 100, 250, 300, 200 },
            { lh_W, WT_lh, 100, 250, 100, 0 },
            { l0f_Whh, WhT_l0f, 500, 125, 512, 0 },
            { l0b_Whh, WhT_l0b, 500, 125, 512, 0 },
            { l1f_Whh, WhT_l1f, 500, 125, 512, 0 },
            { l1b_Whh, WhT_l1b, 500, 125, 512, 0 },
        };
        for (int i = 0; i < 12; i++) {
            ta.j[i].src = js[i].s;  ta.j[i].dst = js[i].d;
            ta.j[i].R = js[i].R;    ta.j[i].C = js[i].C;
            ta.j[i].ldo = js[i].ldo; ta.j[i].coff = js[i].coff;
            ta.j[i].tile0 = n_tr;
            ta.j[i].tiles_x = (js[i].C + 31) / 32;
            n_tr += tiles(js[i].R, js[i].C);
        }
    }
    setup_fused<<<n_tr + 2048 + 9 + 48, 256, 0, stream>>>(
        ta, n_tr, word_ids, upos_ids, wlookup, tlookup, words,
        l0f_b, l0b_b, l1f_b, l1b_b, eh_b, em_b, lm_b,
        b_l0, b_l1, b_s3, WhT_l0f, WhT_l0b, WhT_l1f, WhT_l1b);

    // 1. layer-0 input projections, fused fwd+bwd (K=125, N=1000)
    proj_t<<<BT/MT, 512, 0, stream>>>(words, WT_l0, b_l0, A, 1000, D, D);

    // 2. layer-0 scan -> h0 (C)
    lstm_scan<<<B*2, 1024, 147456, stream>>>(A, WhT_l0f, WhT_l0b, C);

    // 3. layer-1 input projections (K=250, N=1000)
    proj_t<<<BT/MT, 512, 0, stream>>>(C, WT_l1, b_l1, A, 1000, H2, H2);

    // 4. layer-1 scan -> ex (C, overwrites h0)
    lstm_scan<<<B*2, 1024, 147456, stream>>>(A, WhT_l1f, WhT_l1b, C);

    // 5. fused scorer projections: s3 (eh+em+lm, N=300) + lh gathered (N=100)
    proj_s3lh<<<512, 256, 0, stream>>>(C, WT_s3, b_s3, A,
                                       WT_lh, lh_b, rel_head, target_arcs);

    // 6. fused arc + rel scoring/argmax
    arc_rel<<<1024 + BT, 128, 0, stream>>>(A, es_W, es_b, target_arcs, rel_head,
                                           ls_W, ls_b, arc_out, trees_out,
                                           rel_out, preds_out);
}

// Round 8
// 534.216 us; speedup vs baseline: 1.3763x; 1.3763x over previous
//
#include <hip/hip_runtime.h>
#include <hip/hip_bf16.h>
#include <hip/hip_fp16.h>
#include <math.h>

// Problem constants
#define B 32
#define N 128
#define BT (B*N)          // 4096
#define WD 100
#define UD 25
#define D 125             // LSTM hidden per direction
#define G4 (4*D)          // 500 gates
#define H2 (2*D)          // 250
#define HID 100
#define L 50

// Fast, overflow-safe activations on v_exp_f32
__device__ __forceinline__ float fast_tanh(float x) {
    float e = __expf(2.0f * x);
    return 1.0f - 2.0f / (e + 1.0f);
}
__device__ __forceinline__ float fast_sigmoid(float x) {
    return 1.0f / (1.0f + __expf(-x));
}
__device__ __forceinline__ float bcast_lane(float v, int k) {
    return __builtin_bit_cast(float, __builtin_amdgcn_readlane(__builtin_bit_cast(int, v), k));
}
__device__ __forceinline__ unsigned bcast_lane_u(unsigned v, int k) {
    return (unsigned)__builtin_amdgcn_readlane((int)v, k);
}

// pack two f32 into one u32 of 2 f16 (lo, hi), RTNE
__device__ __forceinline__ unsigned pack_f16x2(float lo, float hi) {
    __half hl = __float2half_rn(lo), hh = __float2half_rn(hi);
    unsigned a = (unsigned)__builtin_bit_cast(unsigned short, hl);
    unsigned b = (unsigned)__builtin_bit_cast(unsigned short, hh);
    return a | (b << 16);
}

typedef _Float16 h2_t __attribute__((ext_vector_type(2)));
// acc += w.lo*h.lo + w.hi*h.hi   (fp32 accumulate)
__device__ __forceinline__ float dot2acc(unsigned wu, unsigned hu, float acc) {
#if __has_builtin(__builtin_amdgcn_fdot2)
    return __builtin_amdgcn_fdot2(__builtin_bit_cast(h2_t, wu),
                                  __builtin_bit_cast(h2_t, hu), acc, false);
#else
    h2_t wv = __builtin_bit_cast(h2_t, wu);
    h2_t hv = __builtin_bit_cast(h2_t, hu);
    acc = fmaf((float)wv[0], (float)hv[0], acc);
    acc = fmaf((float)wv[1], (float)hv[1], acc);
    return acc;
#endif
}

// ---------------------------------------------------------------------------
// K_setup: ONE launch for {8 weight transposes, embedding gather, fused
// biases, Whh f16-pair packing}. Grid: [0,TR) transpose tiles,
// [TR,TR+2048) embed, then 9 bias blocks, then 512 pack blocks.
// Pack reads the ORIGINAL Whh (not the transposed copy) so there is no
// cross-block ordering hazard inside the single launch.
// ---------------------------------------------------------------------------
struct TJob { const float* src; float* dst; int R, C, ldo, coff, tile0, tiles_x; };
struct TArgs { TJob j[8]; };

__global__ __launch_bounds__(256)
void setup_fused(TArgs a, int n_tr,
                 const int* __restrict__ wids, const int* __restrict__ uids,
                 const float* __restrict__ wl, const float* __restrict__ tl,
                 float* __restrict__ words,
                 const float* __restrict__ l0f_b, const float* __restrict__ l0b_b,
                 const float* __restrict__ l1f_b, const float* __restrict__ l1b_b,
                 const float* __restrict__ eh_b, const float* __restrict__ em_b,
                 const float* __restrict__ lm_b,
                 float* __restrict__ b_l0, float* __restrict__ b_l1,
                 float* __restrict__ b_s3,
                 const float* __restrict__ s0, const float* __restrict__ s1,
                 const float* __restrict__ s2, const float* __restrict__ s3w,
                 unsigned* __restrict__ d0, unsigned* __restrict__ d1,
                 unsigned* __restrict__ d2, unsigned* __restrict__ d3) {
    __shared__ float tile[32][33];
    int bid = blockIdx.x;
    int tid = threadIdx.x;
    if (bid < n_tr) {                    // ---- transpose tiles ----
        int ji = 0;
        #pragma unroll
        for (int i = 1; i < 8; i++) if (bid >= a.j[i].tile0) ji = i;
        TJob jb = a.j[ji];
        int t = bid - jb.tile0;
        int tx = t % jb.tiles_x, ty = t / jb.tiles_x;
        int txx = tid & 31, tyy = tid >> 5;      // 32 x 8
        int k0 = tx*32, n0 = ty*32;
        #pragma unroll
        for (int dy = 0; dy < 32; dy += 8) {
            int n = n0 + tyy + dy, k = k0 + txx;
            if (n < jb.R && k < jb.C)
                tile[tyy+dy][txx] = jb.src[(size_t)n*jb.C + k];
        }
        __syncthreads();
        #pragma unroll
        for (int dy = 0; dy < 32; dy += 8) {
            int k = k0 + tyy + dy, n = n0 + txx;
            if (k < jb.C && n < jb.R)
                jb.dst[(size_t)k*jb.ldo + jb.coff + n] = tile[txx][tyy+dy];
        }
        return;
    }
    bid -= n_tr;
    if (bid < 2048) {                    // ---- embed: 2 bt per block ----
        int bt = bid*2 + (tid >> 7);
        int t = tid & 127;
        int wid = wids[bt], uid = uids[bt];
        if (t < WD)       words[bt*D + t] = wl[(size_t)wid*WD + t];
        else if (t < D)   words[bt*D + t] = tl[(size_t)uid*UD + (t - WD)];
        return;
    }
    bid -= 2048;
    if (bid < 9) {                       // ---- fused biases ----
        int t = bid*256 + tid;
        if (t < 500)        b_l0[t] = l0f_b[t];
        else if (t < 1000)  b_l0[t] = l0b_b[t-500];
        else if (t < 1500)  b_l1[t-1000] = l1f_b[t-1000];
        else if (t < 2000)  b_l1[t-1000] = l1b_b[t-1500];
        else if (t < 2100)  b_s3[t-2000] = eh_b[t-2000];
        else if (t < 2200)  b_s3[t-2000] = em_b[t-2100];
        else if (t < 2300)  b_s3[t-2000] = lm_b[t-2200];
        return;
    }
    bid -= 9;                            // ---- Whh f16-pair pack (512 blocks) ----
    // WhH[pk][g] (u32, [64][512]) = pack_f16x2(Whh[g][2pk], Whh[g][2pk+1])
    // Whh is [500][125] row-major; zero-fill k>=125, g>=500.
    int e = bid*256 + tid;               // exactly 4*64*512 = 131072
    int m = e >> 15;                     // buffer 0..3
    int r = e & 32767;
    int pk = r >> 9;                     // 0..63
    int g  = r & 511;                    // 0..511
    const float* s = (m == 0) ? s0 : (m == 1) ? s1 : (m == 2) ? s2 : s3w;
    unsigned* dd   = (m == 0) ? d0 : (m == 1) ? d1 : (m == 2) ? d2 : d3;
    float v0 = 0.0f, v1 = 0.0f;
    if (g < 500) {
        int k0 = pk << 1;
        if (k0 < 125)     v0 = s[(size_t)g*125 + k0];
        if (k0 + 1 < 125) v1 = s[(size_t)g*125 + k0 + 1];
    }
    dd[(pk << 9) + g] = pack_f16x2(v0, v1);
}

// ---------------------------------------------------------------------------
// K2: projection GEMM, transposed weights, CPT columns per thread,
//     software-pipelined WT loads (prefetch next k-group).
// ---------------------------------------------------------------------------
#define MT 16
template<int CPT, int BD>
__device__ __forceinline__
void proj_body(const float* __restrict__ x, const float* __restrict__ WT,
               const float* __restrict__ bias, float* __restrict__ out,
               int Ncols, int K, int ldx, const int* __restrict__ gather_idx,
               int blk, float* xs) {
    int m0 = blk * MT;
    for (int e = threadIdx.x; e < MT * K; e += BD) {
        int r = e / K, k = e - r * K;
        int m = m0 + r;
        int row = m;
        if (gather_idx) {
            int bb = m >> 7, np = m & 127;
            row = (bb << 7) + (np == 0 ? 0 : gather_idx[m]);
        }
        xs[k*17 + r] = x[(size_t)row*ldx + k];
    }
    __syncthreads();
    int n0 = threadIdx.x;
    int lane = threadIdx.x & 63;
    float acc[CPT][MT];
    int ncl[CPT];
    #pragma unroll
    for (int j = 0; j < CPT; j++) {
        int n = n0 + j*BD;
        ncl[j] = (n < Ncols) ? n : (Ncols - 1);
        #pragma unroll
        for (int r = 0; r < MT; r++) acc[j][r] = 0.0f;
    }
    float wkc[4][CPT];
    #pragma unroll
    for (int q = 0; q < 4; q++)
        #pragma unroll
        for (int j = 0; j < CPT; j++)
            wkc[q][j] = WT[(size_t)q*Ncols + ncl[j]];
    int k0 = 0;
    for (; k0 + 8 <= K; k0 += 4) {
        float xv = xs[(k0 + (lane >> 4))*17 + (lane & 15)];
        float wkn[4][CPT];
        #pragma unroll
        for (int q = 0; q < 4; q++)
            #pragma unroll
            for (int j = 0; j < CPT; j++)
                wkn[q][j] = WT[(size_t)(k0 + 4 + q)*Ncols + ncl[j]];
        #pragma unroll
        for (int q = 0; q < 4; q++) {
            #pragma unroll
            for (int r = 0; r < 16; r++) {
                float hv = bcast_lane(xv, q*16 + r);
                #pragma unroll
                for (int j = 0; j < CPT; j++)
                    acc[j][r] = fmaf(wkc[q][j], hv, acc[j][r]);
            }
        }
        #pragma unroll
        for (int q = 0; q < 4; q++)
            #pragma unroll
            for (int j = 0; j < CPT; j++)
                wkc[q][j] = wkn[q][j];
    }
    { // last full group
        float xv = xs[(k0 + (lane >> 4))*17 + (lane & 15)];
        #pragma unroll
        for (int q = 0; q < 4; q++) {
            #pragma unroll
            for (int r = 0; r < 16; r++) {
                float hv = bcast_lane(xv, q*16 + r);
                #pragma unroll
                for (int j = 0; j < CPT; j++)
                    acc[j][r] = fmaf(wkc[q][j], hv, acc[j][r]);
            }
        }
        k0 += 4;
    }
    for (; k0 < K; k0++) {
        float xv = xs[k0*17 + (lane & 15)];
        float wk[CPT];
        #pragma unroll
        for (int j = 0; j < CPT; j++) wk[j] = WT[(size_t)k0*Ncols + ncl[j]];
        #pragma unroll
        for (int r = 0; r < 16; r++) {
            float hv = bcast_lane(xv, r);
            #pragma unroll
            for (int j = 0; j < CPT; j++)
                acc[j][r] = fmaf(wk[j], hv, acc[j][r]);
        }
    }
    #pragma unroll
    for (int j = 0; j < CPT; j++) {
        int n = n0 + j*BD;
        if (n < Ncols) {
            float bb = bias[n];
            #pragma unroll
            for (int r = 0; r < MT; r++) out[(size_t)(m0 + r)*Ncols + n] = acc[j][r] + bb;
        }
    }
}

__global__ __launch_bounds__(512)
void proj_t(const float* __restrict__ x, const float* __restrict__ WT,
            const float* __restrict__ bias, float* __restrict__ out,
            int Ncols, int K, int ldx) {
    __shared__ float xs[250 * 17 + 16];
    proj_body<2, 512>(x, WT, bias, out, Ncols, K, ldx, nullptr, blockIdx.x, xs);
}

// fused scorer projections: blocks [0,256) -> s3 (Ncols=300), [256,512) -> lh
__global__ __launch_bounds__(256)
void proj_s3lh(const float* __restrict__ x,
               const float* __restrict__ WTa, const float* __restrict__ ba,
               float* __restrict__ outa,
               const float* __restrict__ WTb, const float* __restrict__ bb,
               float* __restrict__ outb, const int* __restrict__ gather_idx) {
    __shared__ float xs[250 * 17 + 16];
    int job = blockIdx.x >> 8;
    int blk = blockIdx.x & 255;
    if (job == 0)
        proj_body<2, 256>(x, WTa, ba, outa, 300, H2, H2, nullptr, blk, xs);
    else
        proj_body<2, 256>(x, WTb, bb, outb, 100, H2, H2, gather_idx, blk, xs);
}

// ---------------------------------------------------------------------------
// K3: LSTM scan v8 = v2's proven skeleton (116.7 us best) + HALVED weight
// stream: Whh pre-packed to f16 k-pairs (WhH [64][512] u32), consumed by
// v_dot2_f32_f16 with fp32 accumulate. v2's measured limit was its 512
// B/thread/step fp32 L2 re-stream (~1900 cyc/step); f16 pairs cut that to
// 256 B and halve the FMA-loop VALU ops. fp16-W numerics proven by v7
// (absmax unchanged). h stays fp32 in LDS; pairs packed from ds_read_b64.
// Barriers are lgkm-only (proven v3/v6) so x-prefetch is never drained.
// 512 threads = 8 waves. Wave w: k-slice ks=w>>1 (pairs ks*16..+15),
// cols c0..c0+3 (cg=(w&1)*64+lane).
// ---------------------------------------------------------------------------
__global__ __launch_bounds__(512, 2)
void lstm_scan(const float* __restrict__ xgc,
               const unsigned* __restrict__ WhHf, const unsigned* __restrict__ WhHb,
               float* __restrict__ out) {
    int dir = blockIdx.x & 1;
    int b = blockIdx.x >> 1;
    const unsigned* WhH = dir ? WhHb : WhHf;   // [64 pk][512 g] u32 f16-pairs
    int off = dir ? D : 0;
    int t = threadIdx.x;
    int lane = t & 63;
    int w = t >> 6;                 // wave 0..7
    int ks = w >> 1;                // k-slice 0..3 (k rows ks*32..+31)
    int cg = ((w & 1) << 6) + lane; // col-group 0..127
    int c0 = cg << 2;               // first gate col 0..508

    __shared__ __align__(16) float hbuf[128];
    __shared__ __align__(16) float pbuf[4*512];

    const unsigned* wp = WhH + (size_t)(ks*16)*512 + c0;

    const float* xb = xgc + (size_t)b * N * 1000 + dir * 500;
    bool xa = (ks == 0) && (cg < 125);
    float4 zero4 = make_float4(0.f, 0.f, 0.f, 0.f);
    float4 xA = zero4, xB = zero4;          // depth-2 x prefetch
    if (xa) {
        xA = *(const float4*)&xb[(size_t)(dir ? (N-1) : 0)*1000 + c0];
        xB = *(const float4*)&xb[(size_t)(dir ? (N-2) : 1)*1000 + c0];
    }

    if (t < 128) hbuf[t] = 0.0f;
    __syncthreads();

    float c = 0.0f;
    for (int ti = 0; ti < N; ti++) {
        int tt = dir ? (N-1-ti) : ti;
        // issue the 16 weight-pair loads early (independent, pipelined)
        uint4 wq[16];
        #pragma unroll
        for (int p = 0; p < 16; p++)
            wq[p] = *(const uint4*)&wp[(size_t)p*512];
        // h pair pack: lanes 0-15 hold (h[ks*32+2j], h[ks*32+2j+1])
        float2 h2 = *(const float2*)&hbuf[ks*32 + ((lane & 15) << 1)];
        unsigned vhp = pack_f16x2(h2.x, h2.y);
        float4 x_cur = xA;
        float4 xC = zero4;
        if (xa && ti + 2 < N) {
            int tn = dir ? (tt-2) : (tt+2);
            xC = *(const float4*)&xb[(size_t)tn*1000 + c0];
        }
        float a0 = x_cur.x, a1 = x_cur.y, a2 = x_cur.z, a3 = x_cur.w;
        #pragma unroll
        for (int p = 0; p < 16; p++) {
            unsigned hp = bcast_lane_u(vhp, p);
            a0 = dot2acc(wq[p].x, hp, a0);
            a1 = dot2acc(wq[p].y, hp, a1);
            a2 = dot2acc(wq[p].z, hp, a2);
            a3 = dot2acc(wq[p].w, hp, a3);
        }
        xA = xB; xB = xC;
        *(float4*)&pbuf[ks*512 + c0] = make_float4(a0, a1, a2, a3);
        // lgkm-only barrier: weight/x global loads never vmcnt-drained
        asm volatile("s_waitcnt lgkmcnt(0)" ::: "memory");
        __builtin_amdgcn_s_barrier();
        asm volatile("" ::: "memory");
        if (t < D) {
            float iv = pbuf[t]       + pbuf[512+t]       + pbuf[1024+t]       + pbuf[1536+t];
            float fv = pbuf[125+t]   + pbuf[512+125+t]   + pbuf[1024+125+t]   + pbuf[1536+125+t];
            float gv = pbuf[250+t]   + pbuf[512+250+t]   + pbuf[1024+250+t]   + pbuf[1536+250+t];
            float ov = pbuf[375+t]   + pbuf[512+375+t]   + pbuf[1024+375+t]   + pbuf[1536+375+t];
            float si = fast_sigmoid(iv);
            float sf = fast_sigmoid(fv);
            float so = fast_sigmoid(ov);
            c = sf * c + si * fast_tanh(gv);
            float h = so * fast_tanh(c);
            hbuf[t] = h;
            out[(size_t)(b*N + tt)*H2 + off + t] = h;
        }
        asm volatile("s_waitcnt lgkmcnt(0)" ::: "memory");
        __builtin_amdgcn_s_barrier();
        asm volatile("" ::: "memory");
    }
}

// ---------------------------------------------------------------------------
// K4: fused arc + rel. Blocks [0,1024): arc (b, 4-i tile); [1024,5120): rel.
// ---------------------------------------------------------------------------
#define ITILE 4
__global__ __launch_bounds__(128)
void arc_rel(const float* __restrict__ s3,
             const float* __restrict__ esW, const float* __restrict__ esb,
             const int* __restrict__ ta, const float* __restrict__ rh,
             const float* __restrict__ lsW, const float* __restrict__ lsb,
             float* __restrict__ arc_out, float* __restrict__ tree_out,
             float* __restrict__ rel_out, float* __restrict__ pred_out) {
    __shared__ float wms[128 * 101];
    __shared__ float whs[ITILE][HID];
    __shared__ float es[HID];
    __shared__ float sv[128];
    __shared__ int   si[128];
    int j = threadIdx.x;

    if (blockIdx.x < 1024) {             // ---------- arc ----------
        int blk = blockIdx.x;
        int b = blk >> 5, it = blk & 31;
        for (int e = j; e < 128 * HID; e += 128) {
            int r = e / HID, h = e - r * HID;
            wms[r*101 + h] = s3[(size_t)(b*N + r)*300 + 100 + h];
        }
        for (int e = j; e < ITILE * HID; e += 128) {
            int ii = e / HID, h = e - ii * HID;
            whs[ii][h] = s3[(size_t)(b*N + it*ITILE + ii)*300 + h];
        }
        if (j < HID) es[j] = esW[j];
        __syncthreads();
        float eb = esb[0];
        const float* wmr = &wms[j * 101];
        for (int ii = 0; ii < ITILE; ii++) {
            int i = it * ITILE + ii;
            int bi = b * N + i;
            float acc = 0.0f;
            for (int h = 0; h < HID; h++)
                acc = fmaf(es[h], fast_tanh(whs[ii][h] + wmr[h]), acc);
            int tai = (i == 0) ? 0 : ta[bi];
            float score = acc + eb + 1.0f - ((j == tai) ? 1.0f : 0.0f);
            arc_out[(size_t)bi*N + j] = score;
            sv[j] = score; si[j] = j;
            __syncthreads();
            for (int s = 64; s; s >>= 1) {
                if (j < s) {
                    float ov = sv[j+s]; int oi = si[j+s];
                    if (ov > sv[j] || (ov == sv[j] && oi < si[j])) { sv[j] = ov; si[j] = oi; }
                }
                __syncthreads();
            }
            if (j == 0) tree_out[bi] = (float)si[0];
            __syncthreads();
        }
    } else {                             // ---------- rel ----------
        int bt = blockIdx.x - 1024;
        float* tv = es;                  // reuse 100-float buffer
        if (j < HID)
            tv[j] = fast_tanh(s3[(size_t)bt*300 + 200 + j] + rh[(size_t)bt*HID + j]);
        __syncthreads();
        float score = -1e30f;
        if (j < L) {
            float acc = 0.0f;
            const float* wrow = lsW + j*HID;
            for (int h = 0; h < HID; h++) acc = fmaf(wrow[h], tv[h], acc);
            score = acc + lsb[j];
            rel_out[(size_t)bt*L + j] = score;
        }
        sv[j] = score; si[j] = j;
        __syncthreads();
        for (int s = 64; s; s >>= 1) {
            if (j < s) {
                float ov = sv[j+s]; int oi = si[j+s];
                if (ov > sv[j] || (ov == sv[j] && oi < si[j])) { sv[j] = ov; si[j] = oi; }
            }
            __syncthreads();
        }
        if (j == 0) pred_out[bt] = (float)si[0];
    }
}

// ---------------------------------------------------------------------------
extern "C" void kernel_launch(void* const* d_in, const int* in_sizes, int n_in,
                              void* d_out, int out_size, void* d_ws, size_t ws_size,
                              hipStream_t stream) {
    const int*   word_ids    = (const int*)  d_in[0];
    const int*   upos_ids    = (const int*)  d_in[1];
    const int*   target_arcs = (const int*)  d_in[2];
    const float* wlookup     = (const float*)d_in[3];
    const float* tlookup     = (const float*)d_in[4];
    const float* l0f_Wih = (const float*)d_in[5];
    const float* l0f_Whh = (const float*)d_in[6];
    const float* l0f_b   = (const float*)d_in[7];
    const float* l0b_Wih = (const float*)d_in[8];
    const float* l0b_Whh = (const float*)d_in[9];
    const float* l0b_b   = (const float*)d_in[10];
    const float* l1f_Wih = (const float*)d_in[11];
    const float* l1f_Whh = (const float*)d_in[12];
    const float* l1f_b   = (const float*)d_in[13];
    const float* l1b_Wih = (const float*)d_in[14];
    const float* l1b_Whh = (const float*)d_in[15];
    const float* l1b_b   = (const float*)d_in[16];
    const float* eh_W = (const float*)d_in[17];
    const float* eh_b = (const float*)d_in[18];
    const float* em_W = (const float*)d_in[19];
    const float* em_b = (const float*)d_in[20];
    const float* es_W = (const float*)d_in[21];
    const float* es_b = (const float*)d_in[22];
    const float* lh_W = (const float*)d_in[23];
    const float* lh_b = (const float*)d_in[24];
    const float* lm_W = (const float*)d_in[25];
    const float* lm_b = (const float*)d_in[26];
    const float* ls_W = (const float*)d_in[27];
    const float* ls_b = (const float*)d_in[28];

    float* out = (float*)d_out;
    float* trees_out = out;                         // 4096
    float* preds_out = out + BT;                    // 4096
    float* arc_out   = out + 2*BT;                  // 524288
    float* rel_out   = out + 2*BT + BT*N;           // 204800

    float* ws = (float*)d_ws;
    float* A       = ws;                    // 4,096,000: xg fused [m][1000]; later s3 [m][300]
    float* words   = ws + 4096000;          //   512,000
    float* C       = ws + 4608000;          // 1,024,000: h0, then ex
    float* WT_l0   = ws + 5632000;          //   125,000  [125][1000]
    float* WT_l1   = ws + 5757000;          //   250,000  [250][1000]
    float* WT_s3   = ws + 6007000;          //    75,000  [250][300]
    float* WT_lh   = ws + 6082000;          //    25,000  [250][100]
    unsigned* WhH_l0f = (unsigned*)(ws + 6107000);  // 32,768 u32 [64][512] f16-pairs
    unsigned* WhH_l0b = (unsigned*)(ws + 6139768);  // 32,768
    unsigned* WhH_l1f = (unsigned*)(ws + 6172536);  // 32,768
    unsigned* WhH_l1b = (unsigned*)(ws + 6205304);  // 32,768
    float* b_l0    = ws + 6238072;          //     1,000
    float* b_l1    = ws + 6239072;          //     1,000
    float* b_s3    = ws + 6240072;          //     1,000 (300 used)
    float* rel_head = ws + 6241072;         //   409,600  [m][100]
    // total 6,650,672 floats = 26.6 MB

    // 0. single fused setup launch
    TArgs ta{};
    int n_tr = 0;
    {
        auto tiles = [](int R, int C_) { return ((C_+31)/32) * ((R+31)/32); };
        struct { const float* s; float* d; int R, C, ldo, coff; } js[8] = {
            { l0f_Wih, WT_l0, 500, 125, 1000, 0 },
            { l0b_Wih, WT_l0, 500, 125, 1000, 500 },
            { l1f_Wih, WT_l1, 500, 250, 1000, 0 },
            { l1b_Wih, WT_l1, 500, 250, 1000, 500 },
            { eh_W, WT_s3, 100, 250, 300, 0 },
            { em_W, WT_s3, 100, 250, 300, 100 },
            { lm_W, WT_s3, 100, 250, 300, 200 },
            { lh_W, WT_lh, 100, 250, 100, 0 },
        };
        for (int i = 0; i < 8; i++) {
            ta.j[i].src = js[i].s;  ta.j[i].dst = js[i].d;
            ta.j[i].R = js[i].R;    ta.j[i].C = js[i].C;
            ta.j[i].ldo = js[i].ldo; ta.j[i].coff = js[i].coff;
            ta.j[i].tile0 = n_tr;
            ta.j[i].tiles_x = (js[i].C + 31) / 32;
            n_tr += tiles(js[i].R, js[i].C);
        }
    }
    setup_fused<<<n_tr + 2048 + 9 + 512, 256, 0, stream>>>(
        ta, n_tr, word_ids, upos_ids, wlookup, tlookup, words,
        l0f_b, l0b_b, l1f_b, l1b_b, eh_b, em_b, lm_b,
        b_l0, b_l1, b_s3,
        l0f_Whh, l0b_Whh, l1f_Whh, l1b_Whh,
        WhH_l0f, WhH_l0b, WhH_l1f, WhH_l1b);

    // 1. layer-0 input projections, fused fwd+bwd (K=125, N=1000)
    proj_t<<<BT/MT, 512, 0, stream>>>(words, WT_l0, b_l0, A, 1000, D, D);

    // 2. layer-0 scan -> h0 (C)
    lstm_scan<<<B*2, 512, 0, stream>>>(A, WhH_l0f, WhH_l0b, C);

    // 3. layer-1 input projections (K=250, N=1000)
    proj_t<<<BT/MT, 512, 0, stream>>>(C, WT_l1, b_l1, A, 1000, H2, H2);

    // 4. layer-1 scan -> ex (C, overwrites h0)
    lstm_scan<<<B*2, 512, 0, stream>>>(A, WhH_l1f, WhH_l1b, C);

    // 5. fused scorer projections: s3 (eh+em+lm, N=300) + lh gathered (N=100)
    proj_s3lh<<<512, 256, 0, stream>>>(C, WT_s3, b_s3, A,
                                       WT_lh, lh_b, rel_head, target_arcs);

    // 6. fused arc + rel scoring/argmax
    arc_rel<<<1024 + BT, 128, 0, stream>>>(A, es_W, es_b, target_arcs, rel_head,
                                           ls_W, ls_b, arc_out, trees_out,
                                           rel_out, preds_out);
}